// Round 1
// baseline (2185.126 us; speedup 1.0000x reference)
//
#include <hip/hip_runtime.h>
#include <math.h>

#define DI 1024
#define DM 2048
#define DS 16
#define DD 128
#define LSEQ 1024
#define NB 2
#define NTOK (NB * LSEQ) // 2048

// ---------------- tiled f32 GEMM:  C[M,N] = epi( A[M,K] @ B[N,K]^T ) ----------------
// epilogue: 0 = none, 1 = softplus(bias[col] + x)
#define BM 128
#define BN 128
#define BK 16

__global__ __launch_bounds__(256)
void gemm_nt(const float* __restrict__ A, const float* __restrict__ B,
             float* __restrict__ C, int M, int N, int K,
             const float* __restrict__ bias, int epilogue)
{
    __shared__ float As[BK][BM + 4];
    __shared__ float Bs[BK][BN + 4];
    const int bm = blockIdx.y * BM;
    const int bn = blockIdx.x * BN;
    const int tid = threadIdx.x;
    const int tr = tid >> 4;   // 0..15
    const int tc = tid & 15;   // 0..15

    float acc[8][8];
#pragma unroll
    for (int i = 0; i < 8; ++i)
#pragma unroll
        for (int j = 0; j < 8; ++j) acc[i][j] = 0.f;

    for (int k0 = 0; k0 < K; k0 += BK) {
#pragma unroll
        for (int l = 0; l < 2; ++l) {
            int idx = tid + l * 256;      // float4 index over 128x16 tile
            int row = idx >> 2;           // 0..127
            int c4 = (idx & 3) << 2;      // 0,4,8,12
            float4 v = *(const float4*)(A + (size_t)(bm + row) * K + k0 + c4);
            As[c4 + 0][row] = v.x; As[c4 + 1][row] = v.y;
            As[c4 + 2][row] = v.z; As[c4 + 3][row] = v.w;
        }
#pragma unroll
        for (int l = 0; l < 2; ++l) {
            int idx = tid + l * 256;
            int row = idx >> 2;
            int c4 = (idx & 3) << 2;
            float4 v = make_float4(0.f, 0.f, 0.f, 0.f);
            if (bn + row < N)
                v = *(const float4*)(B + (size_t)(bn + row) * K + k0 + c4);
            Bs[c4 + 0][row] = v.x; Bs[c4 + 1][row] = v.y;
            Bs[c4 + 2][row] = v.z; Bs[c4 + 3][row] = v.w;
        }
        __syncthreads();
#pragma unroll
        for (int kk = 0; kk < BK; ++kk) {
            float4 a0 = *(const float4*)&As[kk][tr * 8];
            float4 a1 = *(const float4*)&As[kk][tr * 8 + 4];
            float4 b0 = *(const float4*)&Bs[kk][tc * 8];
            float4 b1 = *(const float4*)&Bs[kk][tc * 8 + 4];
            float av[8] = {a0.x, a0.y, a0.z, a0.w, a1.x, a1.y, a1.z, a1.w};
            float bv[8] = {b0.x, b0.y, b0.z, b0.w, b1.x, b1.y, b1.z, b1.w};
#pragma unroll
            for (int i = 0; i < 8; ++i)
#pragma unroll
                for (int j = 0; j < 8; ++j)
                    acc[i][j] = fmaf(av[i], bv[j], acc[i][j]);
        }
        __syncthreads();
    }

#pragma unroll
    for (int i = 0; i < 8; ++i) {
        int row = bm + tr * 8 + i;
#pragma unroll
        for (int j = 0; j < 8; ++j) {
            int col = bn + tc * 8 + j;
            if (col < N) {
                float v = acc[i][j];
                if (epilogue == 1) {
                    v += bias[col];
                    v = (v > 20.f) ? v : log1pf(__expf(v));
                }
                C[(size_t)row * N + col] = v;
            }
        }
    }
}

// ---------------- causal depthwise conv (K=4) + bias + SiLU ----------------
// in: ab [NTOK, 2*DM], a = cols [0,DM). out: aconv [NTOK, DM]
__global__ __launch_bounds__(256)
void conv_silu(const float* __restrict__ ab, const float* __restrict__ w,
               const float* __restrict__ bias, float* __restrict__ out)
{
    int idx = blockIdx.x * 256 + threadIdx.x;   // over NTOK*DM
    int d = idx & (DM - 1);
    int bt = idx >> 11;                         // token 0..2047
    int b = bt >> 10;
    int t = bt & (LSEQ - 1);
    float acc = bias[d];
#pragma unroll
    for (int k = 0; k < 4; ++k) {
        int tt = t + k - 3;
        if (tt >= 0)
            acc = fmaf(ab[(size_t)(b * LSEQ + tt) * (2 * DM) + d], w[d * 4 + k], acc);
    }
    float s = acc / (1.f + __expf(-acc));
    out[(size_t)bt * DM + d] = s;
}

// ---------------- fused SSM scan + C-contraction + D*a + silu(g) gate ----------------
// one thread per (b,d) channel; h[16] in registers; B/C staged in LDS per t-chunk.
#define TCH 64
__global__ __launch_bounds__(256)
void scan_ssm(const float* __restrict__ sdelta, const float* __restrict__ aconv,
              const float* __restrict__ Bm, const float* __restrict__ Cm,
              const float* __restrict__ ab, const float* __restrict__ A_param,
              const float* __restrict__ D_param, float* __restrict__ z)
{
    __shared__ float Bsh[TCH][DS];
    __shared__ float Csh[TCH][DS];
    const int blk = blockIdx.x;              // 0..15
    const int b = blk >> 3;
    const int d = (blk & 7) * 256 + threadIdx.x;
    const int tid = threadIdx.x;

    float expA[DS], h[DS];
#pragma unroll
    for (int s = 0; s < DS; ++s) {
        expA[s] = __expf(-A_param[d * DS + s]);
        h[s] = 0.f;
    }
    const float Dp = D_param[d];

    for (int t0 = 0; t0 < LSEQ; t0 += TCH) {
        {
            int row = tid >> 2;
            int q = (tid & 3) << 2;
            float4 vb = *(const float4*)(Bm + (size_t)(b * LSEQ + t0 + row) * DS + q);
            float4 vc = *(const float4*)(Cm + (size_t)(b * LSEQ + t0 + row) * DS + q);
            __syncthreads();   // protect previous chunk's readers
            *(float4*)&Bsh[row][q] = vb;
            *(float4*)&Csh[row][q] = vc;
        }
        __syncthreads();
        for (int i = 0; i < TCH; ++i) {
            int t = t0 + i;
            size_t off = (size_t)(b * LSEQ + t) * DM + d;
            float sd = sdelta[off];
            float av = aconv[off];
            float g = ab[(size_t)(b * LSEQ + t) * (2 * DM) + DM + d];
            float t2 = sd * av;
            float acc = 0.f;
#pragma unroll
            for (int s = 0; s < DS; ++s) {
                h[s] = fmaf(sd * expA[s], h[s], t2 * Bsh[i][s]);
                acc = fmaf(h[s], Csh[i][s], acc);
            }
            float o = fmaf(Dp, av, acc);
            float sg = g / (1.f + __expf(-g));
            z[off] = o * sg;
        }
    }
}

extern "C" void kernel_launch(void* const* d_in, const int* in_sizes, int n_in,
                              void* d_out, int out_size, void* d_ws, size_t ws_size,
                              hipStream_t stream) {
    const float* seq    = (const float*)d_in[0];   // [2,1024,1024]
    const float* W_in   = (const float*)d_in[1];   // [4096,1024]
    const float* W_out  = (const float*)d_in[2];   // [1024,2048]
    const float* W_sB   = (const float*)d_in[3];   // [16,2048]
    const float* W_sC   = (const float*)d_in[4];   // [16,2048]
    const float* W_sD1  = (const float*)d_in[5];   // [128,2048]
    const float* W_sD2  = (const float*)d_in[6];   // [2048,128]
    const float* conv_w = (const float*)d_in[7];   // [2048,1,4]
    const float* conv_b = (const float*)d_in[8];   // [2048]
    const float* A_par  = (const float*)d_in[9];   // [2048,16]
    const float* D_par  = (const float*)d_in[10];  // [2048]
    float* out = (float*)d_out;                    // [2,1024,1024]

    char* ws = (char*)d_ws;
    float* ab    = (float*)(ws);                         // [2048,4096] 32MB
    float* aconv = (float*)(ws + 33554432);              // [2048,2048] 16MB
    float* Bmat  = (float*)(ws + 50331648);              // [2048,16]
    float* Cmat  = (float*)(ws + 50462720);              // [2048,16]
    float* d1    = (float*)(ws + 50593792);              // [2048,128]
    float* sdel  = (float*)(ws + 51642368);              // [2048,2048] 16MB
    float* z     = (float*)(ws + 68419584);              // [2048,2048] 16MB

    dim3 blk(256);

    // 1) ab = seq @ W_in^T : M=2048 N=4096 K=1024
    gemm_nt<<<dim3(4096 / BN, 2048 / BM), blk, 0, stream>>>(
        seq, W_in, ab, 2048, 4096, 1024, nullptr, 0);

    // 2) aconv = silu(causal_conv(a) + b)
    conv_silu<<<dim3((NTOK * DM) / 256), blk, 0, stream>>>(ab, conv_w, conv_b, aconv);

    // 3) B = aconv @ W_sB^T : N=16 K=2048
    gemm_nt<<<dim3(1, 2048 / BM), blk, 0, stream>>>(
        aconv, W_sB, Bmat, 2048, 16, 2048, nullptr, 0);
    // 4) C = aconv @ W_sC^T
    gemm_nt<<<dim3(1, 2048 / BM), blk, 0, stream>>>(
        aconv, W_sC, Cmat, 2048, 16, 2048, nullptr, 0);
    // 5) d1 = aconv @ W_sD1^T : N=128 K=2048
    gemm_nt<<<dim3(1, 2048 / BM), blk, 0, stream>>>(
        aconv, W_sD1, d1, 2048, 128, 2048, nullptr, 0);
    // 6) sdelta = softplus(D + d1 @ W_sD2^T) : N=2048 K=128
    gemm_nt<<<dim3(2048 / BN, 2048 / BM), blk, 0, stream>>>(
        d1, W_sD2, sdel, 2048, 2048, 128, D_par, 1);

    // 7) fused scan -> z = (out_ssm) * silu(g)
    scan_ssm<<<dim3(16), blk, 0, stream>>>(sdel, aconv, Bmat, Cmat, ab, A_par, D_par, z);

    // 8) out = z @ W_out^T : M=2048 N=1024 K=2048
    gemm_nt<<<dim3(1024 / BN, 2048 / BM), blk, 0, stream>>>(
        z, W_out, out, 2048, 1024, 2048, nullptr, 0);
}

// Round 2
// 285.952 us; speedup vs baseline: 7.6416x; 7.6416x over previous
//
#include <hip/hip_runtime.h>
#include <math.h>

#define DI 1024
#define DM 2048
#define DS 16
#define LSEQ 1024
#define NB 2
#define NTOK (NB * LSEQ)
#define NC 16          // scan chunks
#define TC 64          // steps per chunk

typedef unsigned short ushort_t;
typedef __attribute__((ext_vector_type(8))) short short8;
typedef __attribute__((ext_vector_type(4))) float f32x4;

__device__ __forceinline__ float bf2f(ushort_t u) {
    union { unsigned u; float f; } c; c.u = (unsigned)u << 16; return c.f;
}
__device__ __forceinline__ ushort_t f2bf(float f) {
    union { float f; unsigned u; } c; c.f = f;
    unsigned r = c.u + 0x7FFFu + ((c.u >> 16) & 1u);
    return (ushort_t)(r >> 16);
}

// ---------------- f32 -> bf16 copy (vectorized x4) ----------------
__global__ __launch_bounds__(256) void cvt_bf16(const float* __restrict__ in,
                                                ushort_t* __restrict__ out, int n4) {
    int i = blockIdx.x * 256 + threadIdx.x;
    if (i < n4) {
        float4 v = ((const float4*)in)[i];
        ushort4 o;
        o.x = f2bf(v.x); o.y = f2bf(v.y); o.z = f2bf(v.z); o.w = f2bf(v.w);
        ((ushort4*)out)[i] = o;
    }
}

// ---------------- pack W_sB(16)+W_sC(16)+W_sD1(128) -> [256][2048] bf16, pad 0 ----------------
__global__ __launch_bounds__(256) void pack_wbcd(const float* __restrict__ Wb,
                                                 const float* __restrict__ Wc,
                                                 const float* __restrict__ Wd1,
                                                 ushort_t* __restrict__ W) {
    int idx = blockIdx.x * 256 + threadIdx.x;      // over 256*2048
    int row = idx >> 11, col = idx & (DM - 1);
    float v = 0.f;
    if (row < 16)       v = Wb[row * DM + col];
    else if (row < 32)  v = Wc[(row - 16) * DM + col];
    else if (row < 160) v = Wd1[(row - 32) * DM + col];
    W[idx] = f2bf(v);
}

// ---------------- bf16 MFMA GEMM: C[M,N] = epi( A[M,K] @ B[N,K]^T ) ----------------
// 128x128 tile, 4 waves (2x2), each wave 64x64 = 4x4 frags of 16x16x32.
// EPI: 0 = f32 out, 1 = bf16 out, 2 = f32 softplus(bias[col]+x)
#define LDT 40   // padded LDS row stride (elems) for BK=32 tile
template<int EPI>
__global__ __launch_bounds__(256) void gemm_bt(
    const ushort_t* __restrict__ A, const ushort_t* __restrict__ B,
    void* __restrict__ Cout, int K, int lda, int ldb, int ldc,
    const float* __restrict__ bias)
{
    __shared__ ushort_t As[128 * LDT];
    __shared__ ushort_t Bs[128 * LDT];
    const int tid = threadIdx.x;
    const int lane = tid & 63;
    const int wv = tid >> 6;
    const int wr = wv >> 1, wc = wv & 1;
    const int bm = blockIdx.y * 128, bn = blockIdx.x * 128;

    f32x4 acc[4][4];
#pragma unroll
    for (int m = 0; m < 4; ++m)
#pragma unroll
        for (int n = 0; n < 4; ++n) acc[m][n] = (f32x4){0.f, 0.f, 0.f, 0.f};

    const int r0 = tid >> 2;             // 0..63
    const int c8 = (tid & 3) * 8;        // 0,8,16,24
    const ushort_t* pA = A + (size_t)(bm + r0) * lda + c8;
    const ushort_t* pB = B + (size_t)(bn + r0) * ldb + c8;

    const int ar = (wr * 64 + (lane & 15)) * LDT + (lane >> 4) * 8;
    const int br = (wc * 64 + (lane & 15)) * LDT + (lane >> 4) * 8;

    for (int k0 = 0; k0 < K; k0 += 32) {
        short8 a0 = *(const short8*)(pA + k0);
        short8 a1 = *(const short8*)(pA + (size_t)64 * lda + k0);
        short8 b0 = *(const short8*)(pB + k0);
        short8 b1 = *(const short8*)(pB + (size_t)64 * ldb + k0);
        __syncthreads();                 // previous iter's frag reads done
        *(short8*)&As[r0 * LDT + c8] = a0;
        *(short8*)&As[(r0 + 64) * LDT + c8] = a1;
        *(short8*)&Bs[r0 * LDT + c8] = b0;
        *(short8*)&Bs[(r0 + 64) * LDT + c8] = b1;
        __syncthreads();
        short8 af[4], bfr[4];
#pragma unroll
        for (int m = 0; m < 4; ++m) af[m] = *(const short8*)&As[ar + m * 16 * LDT];
#pragma unroll
        for (int n = 0; n < 4; ++n) bfr[n] = *(const short8*)&Bs[br + n * 16 * LDT];
#pragma unroll
        for (int m = 0; m < 4; ++m)
#pragma unroll
            for (int n = 0; n < 4; ++n)
                acc[m][n] = __builtin_amdgcn_mfma_f32_16x16x32_bf16(af[m], bfr[n], acc[m][n], 0, 0, 0);
    }

    const int orow = bm + wr * 64 + (lane >> 4) * 4;
    const int ocol = bn + wc * 64 + (lane & 15);
#pragma unroll
    for (int m = 0; m < 4; ++m)
#pragma unroll
        for (int n = 0; n < 4; ++n) {
            int col = ocol + n * 16;
#pragma unroll
            for (int r = 0; r < 4; ++r) {
                int row = orow + m * 16 + r;
                float v = acc[m][n][r];
                if (EPI == 2) {
                    v += bias[col];
                    v = (v > 20.f) ? v : log1pf(__expf(v));
                    ((float*)Cout)[(size_t)row * ldc + col] = v;
                } else if (EPI == 1) {
                    ((ushort_t*)Cout)[(size_t)row * ldc + col] = f2bf(v);
                } else {
                    ((float*)Cout)[(size_t)row * ldc + col] = v;
                }
            }
        }
}

// ---------------- causal depthwise conv (K=4) + bias + SiLU; bf16 in, f32+bf16 out ----------------
__global__ __launch_bounds__(256) void conv_silu(const ushort_t* __restrict__ ab,
                                                 const float* __restrict__ w,
                                                 const float* __restrict__ bias,
                                                 float* __restrict__ outf,
                                                 ushort_t* __restrict__ outh) {
    int idx = blockIdx.x * 256 + threadIdx.x;   // NTOK*DM
    int d = idx & (DM - 1);
    int bt = idx >> 11;
    int b = bt >> 10;
    int t = bt & (LSEQ - 1);
    float acc = bias[d];
#pragma unroll
    for (int k = 0; k < 4; ++k) {
        int tt = t + k - 3;
        if (tt >= 0)
            acc = fmaf(bf2f(ab[(size_t)(b * LSEQ + tt) * (2 * DM) + d]), w[d * 4 + k], acc);
    }
    float s = acc / (1.f + __expf(-acc));
    outf[idx] = s;
    outh[idx] = f2bf(s);
}

// ---------------- scan pass A: per-chunk local scan -> P (products), E (end state) ----------------
__global__ __launch_bounds__(256) void scan_passA(
    const float* __restrict__ sdel, const float* __restrict__ aconv,
    const ushort_t* __restrict__ bcd1, const float* __restrict__ A_param,
    float* __restrict__ P, float* __restrict__ E)
{
    const int tid = threadIdx.x;
    const int d = blockIdx.x * 256 + tid;
    const int c = blockIdx.y;
    const int b = blockIdx.z;
    __shared__ float Bsh[TC][DS];
    {
        int i = tid >> 2, sq = (tid & 3) * 4;
        const ushort_t* src = bcd1 + (size_t)(b * LSEQ + c * TC + i) * 256 + sq;
        ushort4 v = *(const ushort4*)src;
        Bsh[i][sq + 0] = bf2f(v.x); Bsh[i][sq + 1] = bf2f(v.y);
        Bsh[i][sq + 2] = bf2f(v.z); Bsh[i][sq + 3] = bf2f(v.w);
    }
    __syncthreads();
    float expA[DS], h[DS], p[DS];
#pragma unroll
    for (int s = 0; s < DS; ++s) {
        expA[s] = __expf(-A_param[d * DS + s]);
        h[s] = 0.f; p[s] = 1.f;
    }
    const size_t base = (size_t)(b * LSEQ + c * TC) * DM + d;
    for (int i = 0; i < TC; ++i) {
        float sd = sdel[base + (size_t)i * DM];
        float av = aconv[base + (size_t)i * DM];
        float x = sd * av;
#pragma unroll
        for (int s = 0; s < DS; ++s) {
            float cf = sd * expA[s];
            h[s] = fmaf(cf, h[s], x * Bsh[i][s]);
            p[s] *= cf;
        }
    }
    size_t o = ((size_t)(c * NB + b) * DM + d) * DS;
#pragma unroll
    for (int s = 0; s < DS; ++s) { P[o + s] = p[s]; E[o + s] = h[s]; }
}

// ---------------- scan pass B: boundary scan over chunks -> H0 (chunk initial states) ----------------
__global__ __launch_bounds__(256) void scan_passB(const float* __restrict__ P,
                                                  const float* __restrict__ E,
                                                  float* __restrict__ H0) {
    int idx = blockIdx.x * 256 + threadIdx.x;   // b*DM + d
    int b = idx >> 11, d = idx & (DM - 1);
    float h[DS];
#pragma unroll
    for (int s = 0; s < DS; ++s) h[s] = 0.f;
    for (int c = 0; c < NC; ++c) {
        size_t o = ((size_t)(c * NB + b) * DM + d) * DS;
#pragma unroll
        for (int s = 0; s < DS; ++s) {
            H0[o + s] = h[s];
            h[s] = fmaf(P[o + s], h[s], E[o + s]);
        }
    }
}

// ---------------- scan pass C: corrected re-scan + C-contraction + D*a + silu(g) -> z (bf16) ----------------
__global__ __launch_bounds__(256) void scan_passC(
    const float* __restrict__ sdel, const float* __restrict__ aconv,
    const ushort_t* __restrict__ bcd1, const ushort_t* __restrict__ ab,
    const float* __restrict__ A_param, const float* __restrict__ D_param,
    const float* __restrict__ H0, ushort_t* __restrict__ z)
{
    const int tid = threadIdx.x;
    const int d = blockIdx.x * 256 + tid;
    const int c = blockIdx.y;
    const int b = blockIdx.z;
    __shared__ float Bsh[TC][DS];
    __shared__ float Csh[TC][DS];
    {
        int i = tid >> 2, sq = (tid & 3) * 4;
        const ushort_t* src = bcd1 + (size_t)(b * LSEQ + c * TC + i) * 256;
        ushort4 vb = *(const ushort4*)(src + sq);
        ushort4 vc = *(const ushort4*)(src + 16 + sq);
        Bsh[i][sq + 0] = bf2f(vb.x); Bsh[i][sq + 1] = bf2f(vb.y);
        Bsh[i][sq + 2] = bf2f(vb.z); Bsh[i][sq + 3] = bf2f(vb.w);
        Csh[i][sq + 0] = bf2f(vc.x); Csh[i][sq + 1] = bf2f(vc.y);
        Csh[i][sq + 2] = bf2f(vc.z); Csh[i][sq + 3] = bf2f(vc.w);
    }
    __syncthreads();
    float expA[DS], h[DS];
    size_t o0 = ((size_t)(c * NB + b) * DM + d) * DS;
#pragma unroll
    for (int s = 0; s < DS; ++s) {
        expA[s] = __expf(-A_param[d * DS + s]);
        h[s] = H0[o0 + s];
    }
    const float Dp = D_param[d];
    const size_t base = (size_t)(b * LSEQ + c * TC) * DM + d;
    const size_t gbase = (size_t)(b * LSEQ + c * TC) * (2 * DM) + DM + d;
    for (int i = 0; i < TC; ++i) {
        float sd = sdel[base + (size_t)i * DM];
        float av = aconv[base + (size_t)i * DM];
        float g = bf2f(ab[gbase + (size_t)i * (2 * DM)]);
        float x = sd * av;
        float acc = 0.f;
#pragma unroll
        for (int s = 0; s < DS; ++s) {
            float cf = sd * expA[s];
            h[s] = fmaf(cf, h[s], x * Bsh[i][s]);
            acc = fmaf(h[s], Csh[i][s], acc);
        }
        float ov = fmaf(Dp, av, acc);
        float sg = g / (1.f + __expf(-g));
        z[base + (size_t)i * DM] = f2bf(ov * sg);
    }
}

extern "C" void kernel_launch(void* const* d_in, const int* in_sizes, int n_in,
                              void* d_out, int out_size, void* d_ws, size_t ws_size,
                              hipStream_t stream) {
    const float* seq    = (const float*)d_in[0];
    const float* W_in   = (const float*)d_in[1];
    const float* W_out  = (const float*)d_in[2];
    const float* W_sB   = (const float*)d_in[3];
    const float* W_sC   = (const float*)d_in[4];
    const float* W_sD1  = (const float*)d_in[5];
    const float* W_sD2  = (const float*)d_in[6];
    const float* conv_w = (const float*)d_in[7];
    const float* conv_b = (const float*)d_in[8];
    const float* A_par  = (const float*)d_in[9];
    const float* D_par  = (const float*)d_in[10];
    float* out = (float*)d_out;

    char* ws = (char*)d_ws;
    const size_t MiB = 1024 * 1024;
    ushort_t* ab_bf    = (ushort_t*)(ws);                 // [2048][4096] 16 MiB @0
    float*    aconv_f  = (float*)(ws + 16 * MiB);         // [2048][2048] 16 MiB @16
    ushort_t* aconv_h  = (ushort_t*)(ws + 32 * MiB);      // 8 MiB @32 (dead after small-gemm)
    float*    H0       = (float*)(ws + 32 * MiB);         // 8 MiB @32 (passB->passC)
    float*    sdel     = (float*)(ws + 40 * MiB);         // 16 MiB @40 (dead after passC)
    ushort_t* W_out_bf = (ushort_t*)(ws + 40 * MiB);      // 4 MiB @40 (after passC)
    ushort_t* z_bf     = (ushort_t*)(ws + 56 * MiB);      // 8 MiB @56
    ushort_t* seq_bf   = (ushort_t*)(ws + 64 * MiB);      // 4 MiB @64 (dead after G1)
    ushort_t* W_in_bf  = (ushort_t*)(ws + 68 * MiB);      // 8 MiB @68 (dead after G1)
    ushort_t* Wbcd     = (ushort_t*)(ws + 64 * MiB);      // 1 MiB @64 (after G1, dead after small)
    ushort_t* W_sD2_bf = (ushort_t*)(ws + 65 * MiB);      // 0.5 MiB @65 (dead after G6)
    float*    P        = (float*)(ws + 64 * MiB);         // 8 MiB @64 (passA->passB)
    float*    E        = (float*)(ws + 72 * MiB);         // 8 MiB @72
    ushort_t* bcd1     = (ushort_t*)(ws + 80 * MiB);      // [2048][256] 1 MiB @80

    dim3 blk(256);

    cvt_bf16<<<dim3(2048), blk, 0, stream>>>(seq, seq_bf, NTOK * DI / 4);
    cvt_bf16<<<dim3(4096), blk, 0, stream>>>(W_in, W_in_bf, 2 * DM * DI / 4);
    // G1: ab = seq @ W_in^T  (bf16 out)  M=2048 N=4096 K=1024
    gemm_bt<1><<<dim3(32, 16), blk, 0, stream>>>(seq_bf, W_in_bf, ab_bf, 1024, DI, DI, 2 * DM, nullptr);

    pack_wbcd<<<dim3(2048), blk, 0, stream>>>(W_sB, W_sC, W_sD1, Wbcd);
    cvt_bf16<<<dim3(256), blk, 0, stream>>>(W_sD2, W_sD2_bf, DM * 128 / 4);

    conv_silu<<<dim3(NTOK * DM / 256), blk, 0, stream>>>(ab_bf, conv_w, conv_b, aconv_f, aconv_h);

    // small fused: bcd1 = aconv @ [W_sB;W_sC;W_sD1;0]^T  (bf16 out)  N=256 K=2048
    gemm_bt<1><<<dim3(2, 16), blk, 0, stream>>>(aconv_h, Wbcd, bcd1, DM, DM, DM, 256, nullptr);

    // G6: sdel = softplus(D + d1 @ W_sD2^T)  (f32 out)  N=2048 K=128, A = bcd1 cols 32.. (lda=256)
    gemm_bt<2><<<dim3(16, 16), blk, 0, stream>>>(bcd1 + 32, W_sD2_bf, sdel, 128, 256, 128, DM, D_par);

    // scan (3-pass chunked)
    scan_passA<<<dim3(8, NC, NB), blk, 0, stream>>>(sdel, aconv_f, bcd1, A_par, P, E);
    scan_passB<<<dim3(16), blk, 0, stream>>>(P, E, H0);
    scan_passC<<<dim3(8, NC, NB), blk, 0, stream>>>(sdel, aconv_f, bcd1, ab_bf, A_par, D_par, H0, z_bf);

    // G8: out = z @ W_out^T  (f32 out)  N=1024 K=2048
    cvt_bf16<<<dim3(2048), blk, 0, stream>>>(W_out, W_out_bf, DI * DM / 4);
    gemm_bt<0><<<dim3(8, 16), blk, 0, stream>>>(z_bf, W_out_bf, out, DM, DM, DM, DI, nullptr);
}

// Round 3
// 214.555 us; speedup vs baseline: 10.1845x; 1.3328x over previous
//
#include <hip/hip_runtime.h>
#include <math.h>

#define DI 1024
#define DM 2048
#define DS 16
#define LSEQ 1024
#define NB 2
#define NTOK (NB * LSEQ)
#define NC 16          // scan chunks
#define TC 64          // steps per chunk

typedef unsigned short ushort_t;
typedef __attribute__((ext_vector_type(8))) short short8;
typedef __attribute__((ext_vector_type(4))) float f32x4;

__device__ __forceinline__ float bf2f(ushort_t u) {
    union { unsigned u; float f; } c; c.u = (unsigned)u << 16; return c.f;
}
__device__ __forceinline__ ushort_t f2bf(float f) {
    union { float f; unsigned u; } c; c.f = f;
    unsigned r = c.u + 0x7FFFu + ((c.u >> 16) & 1u);
    return (ushort_t)(r >> 16);
}

// async global->LDS, 16B per lane. LDS dest is wave-uniform base + lane*16.
__device__ __forceinline__ void gload16(const void* g, void* l) {
    __builtin_amdgcn_global_load_lds(
        (const __attribute__((address_space(1))) void*)g,
        (__attribute__((address_space(3))) void*)l, 16, 0, 0);
}

// ---------------- prep: all f32->bf16 conversions + weight packing, one kernel ----------------
__device__ __forceinline__ void cvt4(const float* __restrict__ in,
                                     ushort_t* __restrict__ out, int q) {
    float4 v = ((const float4*)in)[q];
    ushort4 o;
    o.x = f2bf(v.x); o.y = f2bf(v.y); o.z = f2bf(v.z); o.w = f2bf(v.w);
    ((ushort4*)out)[q] = o;
}

__global__ __launch_bounds__(256) void prep(
    const float* __restrict__ seq, const float* __restrict__ W_in,
    const float* __restrict__ W_out, const float* __restrict__ W_sD2,
    const float* __restrict__ Wb, const float* __restrict__ Wc,
    const float* __restrict__ Wd1,
    ushort_t* __restrict__ seq_bf, ushort_t* __restrict__ W_in_bf,
    ushort_t* __restrict__ W_out_bf, ushort_t* __restrict__ W_sD2_bf,
    ushort_t* __restrict__ wbcd)
{
    int q = blockIdx.x * 256 + threadIdx.x;
    if (q < 524288)        cvt4(seq,   seq_bf,   q);
    else if (q < 1572864)  cvt4(W_in,  W_in_bf,  q - 524288);
    else if (q < 2097152)  cvt4(W_out, W_out_bf, q - 1572864);
    else if (q < 2162688)  cvt4(W_sD2, W_sD2_bf, q - 2097152);
    else {
        int p = q - 2162688;          // quad within wbcd [256][2048]
        int idx = p * 4;
        int row = idx >> 11, col = idx & (DM - 1);
        float4 v = make_float4(0.f, 0.f, 0.f, 0.f);
        if (row < 16)       v = *(const float4*)&Wb[row * DM + col];
        else if (row < 32)  v = *(const float4*)&Wc[(row - 16) * DM + col];
        else if (row < 160) v = *(const float4*)&Wd1[(row - 32) * DM + col];
        ushort4 o;
        o.x = f2bf(v.x); o.y = f2bf(v.y); o.z = f2bf(v.z); o.w = f2bf(v.w);
        ((ushort4*)wbcd)[p] = o;
    }
}

// ---------------- bf16 MFMA GEMM (m97 structure): C[M,N] = epi( A[M,K] @ B[N,K]^T ) ----------------
// 128x128 tile, 4 waves (2x2), 16x16x32 mfma, global_load_lds staging, linear LDS
// with both-sides XOR swizzle: LDS slot sl holds global k-slot sl ^ ((row>>1)&3).
// EPI: 0 = f32 out, 1 = bf16 out, 3 = bf16 softplus(bias[col]+x), 4 = f32 split-K partial
template<int EPI>
__global__ __launch_bounds__(256) void gemm_bt(
    const ushort_t* __restrict__ A, const ushort_t* __restrict__ B,
    void* __restrict__ Cout, int K, int lda, int ldb, int ldc,
    const float* __restrict__ bias, float* __restrict__ Cpart)
{
    __shared__ ushort_t As[128 * 32];
    __shared__ ushort_t Bs[128 * 32];
    const int tid = threadIdx.x;
    const int lane = tid & 63;
    const int wv = tid >> 6;
    const int wr = wv >> 1, wc = wv & 1;
    const int bm = blockIdx.y * 128, bn = blockIdx.x * 128;

    int kbeg = 0, kend = K;
    if (EPI == 4) { int ks = K / gridDim.z; kbeg = blockIdx.z * ks; kend = kbeg + ks; }

    f32x4 acc[4][4];
#pragma unroll
    for (int m = 0; m < 4; ++m)
#pragma unroll
        for (int n = 0; n < 4; ++n) acc[m][n] = (f32x4){0.f, 0.f, 0.f, 0.f};

    // staging: each wave stages rows [wv*16, wv*16+16) and [64+wv*16, ...) of A and B.
    // lane i covers (row = base + i/4, slot = i&3); global slot pre-swizzled.
    const int r_lo = lane >> 2;
    const int s_l = lane & 3;
    const int rowA0 = wv * 16 + r_lo;
    const int rowA1 = 64 + wv * 16 + r_lo;
    const int sg0 = s_l ^ ((rowA0 >> 1) & 3);
    const int sg1 = s_l ^ ((rowA1 >> 1) & 3);
    const ushort_t* gA0 = A + (size_t)(bm + rowA0) * lda + sg0 * 8;
    const ushort_t* gA1 = A + (size_t)(bm + rowA1) * lda + sg1 * 8;
    const ushort_t* gB0 = B + (size_t)(bn + rowA0) * ldb + sg0 * 8;
    const ushort_t* gB1 = B + (size_t)(bn + rowA1) * ldb + sg1 * 8;
    ushort_t* lA0 = &As[(wv * 16) * 32];
    ushort_t* lA1 = &As[(64 + wv * 16) * 32];
    ushort_t* lB0 = &Bs[(wv * 16) * 32];
    ushort_t* lB1 = &Bs[(64 + wv * 16) * 32];

    for (int k = kbeg; k < kend; k += 32) {
        gload16(gA0 + k, lA0);
        gload16(gA1 + k, lA1);
        gload16(gB0 + k, lB0);
        gload16(gB1 + k, lB1);
        __syncthreads();                    // drains vmcnt: tile resident
        short8 af[4], bfr[4];
#pragma unroll
        for (int m = 0; m < 4; ++m) {
            int row = wr * 64 + m * 16 + (lane & 15);
            int sl = (lane >> 4) ^ ((row >> 1) & 3);
            af[m] = *(const short8*)&As[row * 32 + sl * 8];
        }
#pragma unroll
        for (int n = 0; n < 4; ++n) {
            int row = wc * 64 + n * 16 + (lane & 15);
            int sl = (lane >> 4) ^ ((row >> 1) & 3);
            bfr[n] = *(const short8*)&Bs[row * 32 + sl * 8];
        }
#pragma unroll
        for (int m = 0; m < 4; ++m)
#pragma unroll
            for (int n = 0; n < 4; ++n)
                acc[m][n] = __builtin_amdgcn_mfma_f32_16x16x32_bf16(af[m], bfr[n], acc[m][n], 0, 0, 0);
        __syncthreads();                    // LDS safe to overwrite
    }

    const int orow = bm + wr * 64 + ((lane >> 4) << 2);
    const int ocol = bn + wc * 64 + (lane & 15);
#pragma unroll
    for (int m = 0; m < 4; ++m)
#pragma unroll
        for (int n = 0; n < 4; ++n) {
            int col = ocol + n * 16;
#pragma unroll
            for (int r = 0; r < 4; ++r) {
                int row = orow + m * 16 + r;
                float v = acc[m][n][r];
                if (EPI == 3) {
                    v += bias[col];
                    v = (v > 20.f) ? v : log1pf(__expf(v));
                    ((ushort_t*)Cout)[(size_t)row * ldc + col] = f2bf(v);
                } else if (EPI == 1) {
                    ((ushort_t*)Cout)[(size_t)row * ldc + col] = f2bf(v);
                } else if (EPI == 4) {
                    (Cpart + (size_t)blockIdx.z * (2048 * 256))[(size_t)row * ldc + col] = v;
                } else {
                    ((float*)Cout)[(size_t)row * ldc + col] = v;
                }
            }
        }
}

// ---------------- split-K reduce -> bf16 bcd1 ----------------
__global__ __launch_bounds__(256) void reduce_bcd(const float* __restrict__ part,
                                                  ushort_t* __restrict__ outh)
{
    int q = blockIdx.x * 256 + threadIdx.x;   // over 131072 quads
    float4 s = ((const float4*)part)[q];
#pragma unroll
    for (int z = 1; z < 4; ++z) {
        float4 v = ((const float4*)part)[q + z * 131072];
        s.x += v.x; s.y += v.y; s.z += v.z; s.w += v.w;
    }
    ushort4 o;
    o.x = f2bf(s.x); o.y = f2bf(s.y); o.z = f2bf(s.z); o.w = f2bf(s.w);
    ((ushort4*)outh)[q] = o;
}

// ---------------- causal depthwise conv (K=4) + bias + SiLU; bf16 in/out ----------------
__global__ __launch_bounds__(256) void conv_silu(const ushort_t* __restrict__ ab,
                                                 const float* __restrict__ w,
                                                 const float* __restrict__ bias,
                                                 ushort_t* __restrict__ outh) {
    int idx = blockIdx.x * 256 + threadIdx.x;   // NTOK*DM
    int d = idx & (DM - 1);
    int bt = idx >> 11;
    int b = bt >> 10;
    int t = bt & (LSEQ - 1);
    float acc = bias[d];
#pragma unroll
    for (int k = 0; k < 4; ++k) {
        int tt = t + k - 3;
        if (tt >= 0)
            acc = fmaf(bf2f(ab[(size_t)(b * LSEQ + tt) * (2 * DM) + d]), w[d * 4 + k], acc);
    }
    float s = acc / (1.f + __expf(-acc));
    outh[idx] = f2bf(s);
}

// ---------------- scan pass A: per-chunk local scan -> P (products), E (end state) ----------------
__global__ __launch_bounds__(256) void scan_passA(
    const ushort_t* __restrict__ sdel, const ushort_t* __restrict__ aconv,
    const ushort_t* __restrict__ bcd1, const float* __restrict__ A_param,
    float* __restrict__ P, float* __restrict__ E)
{
    const int tid = threadIdx.x;
    const int d = blockIdx.x * 256 + tid;
    const int c = blockIdx.y;
    const int b = blockIdx.z;
    __shared__ float Bsh[TC][DS];
    {
        int i = tid >> 2, sq = (tid & 3) * 4;
        const ushort_t* src = bcd1 + (size_t)(b * LSEQ + c * TC + i) * 256 + sq;
        ushort4 v = *(const ushort4*)src;
        Bsh[i][sq + 0] = bf2f(v.x); Bsh[i][sq + 1] = bf2f(v.y);
        Bsh[i][sq + 2] = bf2f(v.z); Bsh[i][sq + 3] = bf2f(v.w);
    }
    __syncthreads();
    float expA[DS], h[DS], p[DS];
#pragma unroll
    for (int s = 0; s < DS; ++s) {
        expA[s] = __expf(-A_param[d * DS + s]);
        h[s] = 0.f; p[s] = 1.f;
    }
    const size_t base = (size_t)(b * LSEQ + c * TC) * DM + d;
    for (int i = 0; i < TC; ++i) {
        float sd = bf2f(sdel[base + (size_t)i * DM]);
        float av = bf2f(aconv[base + (size_t)i * DM]);
        float x = sd * av;
#pragma unroll
        for (int s = 0; s < DS; ++s) {
            float cf = sd * expA[s];
            h[s] = fmaf(cf, h[s], x * Bsh[i][s]);
            p[s] *= cf;
        }
    }
    size_t o = ((size_t)(c * NB + b) * DM + d) * DS;
#pragma unroll
    for (int s = 0; s < DS; ++s) { P[o + s] = p[s]; E[o + s] = h[s]; }
}

// ---------------- scan pass B: boundary scan over chunks (coalesced, 1 thread per (b,d,s)) ----------------
__global__ __launch_bounds__(256) void scan_passB(const float* __restrict__ P,
                                                  const float* __restrict__ E,
                                                  float* __restrict__ H0) {
    size_t idx = blockIdx.x * 256 + threadIdx.x;   // over NB*DM*DS = 65536
    float h = 0.f;
    const size_t stride = (size_t)NB * DM * DS;
    size_t o = idx;
    for (int c = 0; c < NC; ++c, o += stride) {
        H0[o] = h;
        h = fmaf(P[o], h, E[o]);
    }
}

// ---------------- scan pass C: corrected re-scan + C-contraction + D*a + silu(g) -> z (bf16) ----------------
__global__ __launch_bounds__(256) void scan_passC(
    const ushort_t* __restrict__ sdel, const ushort_t* __restrict__ aconv,
    const ushort_t* __restrict__ bcd1, const ushort_t* __restrict__ ab,
    const float* __restrict__ A_param, const float* __restrict__ D_param,
    const float* __restrict__ H0, ushort_t* __restrict__ z)
{
    const int tid = threadIdx.x;
    const int d = blockIdx.x * 256 + tid;
    const int c = blockIdx.y;
    const int b = blockIdx.z;
    __shared__ float Bsh[TC][DS];
    __shared__ float Csh[TC][DS];
    {
        int i = tid >> 2, sq = (tid & 3) * 4;
        const ushort_t* src = bcd1 + (size_t)(b * LSEQ + c * TC + i) * 256;
        ushort4 vb = *(const ushort4*)(src + sq);
        ushort4 vc = *(const ushort4*)(src + 16 + sq);
        Bsh[i][sq + 0] = bf2f(vb.x); Bsh[i][sq + 1] = bf2f(vb.y);
        Bsh[i][sq + 2] = bf2f(vb.z); Bsh[i][sq + 3] = bf2f(vb.w);
        Csh[i][sq + 0] = bf2f(vc.x); Csh[i][sq + 1] = bf2f(vc.y);
        Csh[i][sq + 2] = bf2f(vc.z); Csh[i][sq + 3] = bf2f(vc.w);
    }
    __syncthreads();
    float expA[DS], h[DS];
    size_t o0 = ((size_t)(c * NB + b) * DM + d) * DS;
#pragma unroll
    for (int s = 0; s < DS; ++s) {
        expA[s] = __expf(-A_param[d * DS + s]);
        h[s] = H0[o0 + s];
    }
    const float Dp = D_param[d];
    const size_t base = (size_t)(b * LSEQ + c * TC) * DM + d;
    const size_t gbase = (size_t)(b * LSEQ + c * TC) * (2 * DM) + DM + d;
    for (int i = 0; i < TC; ++i) {
        float sd = bf2f(sdel[base + (size_t)i * DM]);
        float av = bf2f(aconv[base + (size_t)i * DM]);
        float g = bf2f(ab[gbase + (size_t)i * (2 * DM)]);
        float x = sd * av;
        float acc = 0.f;
#pragma unroll
        for (int s = 0; s < DS; ++s) {
            float cf = sd * expA[s];
            h[s] = fmaf(cf, h[s], x * Bsh[i][s]);
            acc = fmaf(h[s], Csh[i][s], acc);
        }
        float ov = fmaf(Dp, av, acc);
        float sg = g / (1.f + __expf(-g));
        z[base + (size_t)i * DM] = f2bf(ov * sg);
    }
}

extern "C" void kernel_launch(void* const* d_in, const int* in_sizes, int n_in,
                              void* d_out, int out_size, void* d_ws, size_t ws_size,
                              hipStream_t stream) {
    const float* seq    = (const float*)d_in[0];
    const float* W_in   = (const float*)d_in[1];
    const float* W_out  = (const float*)d_in[2];
    const float* W_sB   = (const float*)d_in[3];
    const float* W_sC   = (const float*)d_in[4];
    const float* W_sD1  = (const float*)d_in[5];
    const float* W_sD2  = (const float*)d_in[6];
    const float* conv_w = (const float*)d_in[7];
    const float* conv_b = (const float*)d_in[8];
    const float* A_par  = (const float*)d_in[9];
    const float* D_par  = (const float*)d_in[10];
    float* out = (float*)d_out;

    char* ws = (char*)d_ws;
    const size_t MiB = 1024 * 1024;
    ushort_t* ab_bf    = (ushort_t*)(ws);                        // 16 MiB @0   (G1 -> conv, passC)
    ushort_t* aconv_h  = (ushort_t*)(ws + 16 * MiB);             //  8 MiB @16  (conv -> smallK, passA/C)
    ushort_t* sdel_h   = (ushort_t*)(ws + 24 * MiB);             //  8 MiB @24  (G6 -> passA/C)
    ushort_t* W_out_bf = (ushort_t*)(ws + 32 * MiB);             //  4 MiB @32  (prep -> G8)
    ushort_t* bcd1     = (ushort_t*)(ws + 36 * MiB);             //  1 MiB @36  (reduce -> G6, passA/C)
    ushort_t* W_sD2_bf = (ushort_t*)(ws + 37 * MiB);             // .5 MiB @37  (prep -> G6)
    ushort_t* Wbcd     = (ushort_t*)(ws + 37 * MiB + 512*1024);  //  1 MiB      (prep -> smallK)
    ushort_t* seq_bf   = (ushort_t*)(ws + 39 * MiB);             //  4 MiB @39  (prep -> G1; dead after)
    ushort_t* W_in_bf  = (ushort_t*)(ws + 43 * MiB);             //  8 MiB @43  (prep -> G1; dead after)
    float*    part     = (float*)(ws + 51 * MiB);                //  8 MiB @51  (smallK -> reduce; dead)
    float*    P        = (float*)(ws + 39 * MiB);                //  8 MiB @39  (passA -> passB; over seq/W_in)
    float*    E        = (float*)(ws + 47 * MiB);                //  8 MiB @47  (passA -> passB; over W_in/part)
    float*    H0       = (float*)(ws + 55 * MiB);                //  8 MiB @55  (passB -> passC; over part tail)
    ushort_t* z_bf     = (ushort_t*)(ws + 63 * MiB);             //  8 MiB @63  (passC -> G8)

    dim3 blk(256);

    // 1) all conversions + weight packing
    prep<<<dim3(8960), blk, 0, stream>>>(seq, W_in, W_out, W_sD2, W_sB, W_sC, W_sD1,
                                         seq_bf, W_in_bf, W_out_bf, W_sD2_bf, Wbcd);

    // 2) G1: ab = seq @ W_in^T (bf16 out)  M=2048 N=4096 K=1024
    gemm_bt<1><<<dim3(32, 16), blk, 0, stream>>>(seq_bf, W_in_bf, ab_bf, 1024, DI, DI, 2 * DM, nullptr, nullptr);

    // 3) aconv = silu(causal_conv(a) + b) (bf16)
    conv_silu<<<dim3(NTOK * DM / 256), blk, 0, stream>>>(ab_bf, conv_w, conv_b, aconv_h);

    // 4) split-K small gemm: part[z] = aconv @ Wbcd^T slice  N=256 K=512/slice
    gemm_bt<4><<<dim3(2, 16, 4), blk, 0, stream>>>(aconv_h, Wbcd, nullptr, DM, DM, DM, 256, nullptr, part);

    // 5) bcd1 = sum_z part[z] (bf16)
    reduce_bcd<<<dim3(512), blk, 0, stream>>>(part, bcd1);

    // 6) G6: sdel = softplus(D + d1 @ W_sD2^T) (bf16 out)  N=2048 K=128
    gemm_bt<3><<<dim3(16, 16), blk, 0, stream>>>(bcd1 + 32, W_sD2_bf, sdel_h, 128, 256, 128, DM, D_par, nullptr);

    // 7-9) chunked scan
    scan_passA<<<dim3(8, NC, NB), blk, 0, stream>>>(sdel_h, aconv_h, bcd1, A_par, P, E);
    scan_passB<<<dim3(256), blk, 0, stream>>>(P, E, H0);
    scan_passC<<<dim3(8, NC, NB), blk, 0, stream>>>(sdel_h, aconv_h, bcd1, ab_bf, A_par, D_par, H0, z_bf);

    // 10) G8: out = z @ W_out^T (f32 out)  N=1024 K=2048
    gemm_bt<0><<<dim3(8, 16), blk, 0, stream>>>(z_bf, W_out_bf, out, DM, DM, DM, DI, nullptr, nullptr);
}